// Round 2
// baseline (595.345 us; speedup 1.0000x reference)
//
#include <hip/hip_runtime.h>
#include <hip/hip_bf16.h>

// Problem constants (B,C,H,W)=(8,256,128,128), M=64, K=5, S=2, nH=nW=64
#define Bq 8
#define Cq 256
#define Hq 128
#define Wq 128
#define Mq 64
#define KK 25
#define NH 64
#define NW 64
#define HWq (Hq*Wq)      // 16384
#define NHW (NH*NW)      // 4096

// ---------------- Kernel A: 1x1 conv (C=256 -> M=64) + bias ----------------
// grid: 512 blocks (b * 64 pixel-tiles), 256 threads; thread = 1 pixel, 64 m-accumulators
__global__ __launch_bounds__(256) void conv1x1_kernel(
    const float* __restrict__ x, const float* __restrict__ w1,
    const float* __restrict__ b1, float* __restrict__ t1) {
  __shared__ float wlds[64 * 64];   // chunk: [c_local*64 + m]
  const int tid = threadIdx.x;
  const int b   = blockIdx.x >> 6;
  const int p   = ((blockIdx.x & 63) << 8) + tid;
  const float* xb = x + (size_t)b * Cq * HWq + p;

  float acc[64];
#pragma unroll
  for (int m = 0; m < 64; ++m) acc[m] = 0.f;

  for (int cc = 0; cc < 4; ++cc) {
    __syncthreads();
    // load w1 chunk: w1[m][cc*64 + c] -> wlds[c*64 + m]; global reads coalesced in 64-runs
#pragma unroll
    for (int i = 0; i < 16; ++i) {
      int e = tid + i * 256;          // e = m*64 + c
      int m = e >> 6, c = e & 63;
      wlds[c * 64 + m] = w1[m * Cq + cc * 64 + c];
    }
    __syncthreads();
#pragma unroll 4
    for (int c = 0; c < 64; ++c) {
      float xv = xb[(cc * 64 + c) * HWq];
#pragma unroll
      for (int m4 = 0; m4 < 16; ++m4) {
        float4 w = *(const float4*)&wlds[c * 64 + m4 * 4];
        acc[m4 * 4 + 0] += xv * w.x;
        acc[m4 * 4 + 1] += xv * w.y;
        acc[m4 * 4 + 2] += xv * w.z;
        acc[m4 * 4 + 3] += xv * w.w;
      }
    }
  }
  float* tb = t1 + (size_t)b * Mq * HWq + p;
#pragma unroll
  for (int m = 0; m < 64; ++m) tb[m * HWq] = acc[m] + b1[m];
}

// ------- Kernel B: 3x3 stride-2 conv (M=64 -> 25) + bias + softmax(25) -------
// grid: 512 blocks (b*64 + oh), 64 threads (ow); thread computes all 25 channels
__global__ __launch_bounds__(64) void encoder_kernel(
    const float* __restrict__ t1, const float* __restrict__ w2,
    const float* __restrict__ b2, float* __restrict__ ker) {
  __shared__ float w2_lds[KK * Mq * 9];   // 14400 floats, direct copy [k][m][3][3]
  const int tid = threadIdx.x;            // = ow
#pragma unroll 5
  for (int i = 0; i < 225; ++i) w2_lds[tid + i * 64] = w2[tid + i * 64];
  __syncthreads();

  const int b  = blockIdx.x >> 6;
  const int oh = blockIdx.x & 63;
  const int ow = tid;
  const float* tb = t1 + (size_t)b * Mq * HWq;

  float acc[KK];
#pragma unroll
  for (int k = 0; k < KK; ++k) acc[k] = b2[k];

  for (int m = 0; m < Mq; ++m) {
#pragma unroll
    for (int dh = 0; dh < 3; ++dh) {
      int ih = 2 * oh + dh - 1;
      if ((unsigned)ih < (unsigned)Hq) {
#pragma unroll
        for (int dw = 0; dw < 3; ++dw) {
          int iw = 2 * ow + dw - 1;
          float v = ((unsigned)iw < (unsigned)Wq) ? tb[m * HWq + ih * Wq + iw] : 0.f;
#pragma unroll
          for (int k = 0; k < KK; ++k)
            acc[k] += v * w2_lds[k * (Mq * 9) + m * 9 + dh * 3 + dw];
        }
      }
    }
  }
  // softmax over 25
  float mx = acc[0];
#pragma unroll
  for (int k = 1; k < KK; ++k) mx = fmaxf(mx, acc[k]);
  float s = 0.f;
#pragma unroll
  for (int k = 0; k < KK; ++k) { acc[k] = __expf(acc[k] - mx); s += acc[k]; }
  float inv = 1.f / s;
  float* kb = ker + (size_t)b * KK * NHW + oh * NW + ow;
#pragma unroll
  for (int k = 0; k < KK; ++k) kb[k * NHW] = acc[k] * inv;
}

// --------- Kernel C: CARAFE reassembly: out[b,c,oh,ow] = sum_k ker * patch ---------
// grid: 512 blocks (b*64 + oh), 256 threads = 64 ow x 4 c-subgroups
__global__ __launch_bounds__(256) void reassemble_kernel(
    const float* __restrict__ x, const float* __restrict__ ker,
    float* __restrict__ out) {
  __shared__ float klds[KK][NW];
  const int b  = blockIdx.x >> 6;
  const int oh = blockIdx.x & 63;
  const int tid = threadIdx.x;
  for (int i = tid; i < KK * NW; i += 256) {
    int k = i >> 6, ow = i & 63;
    klds[k][ow] = ker[(size_t)(b * KK + k) * NHW + oh * NW + ow];
  }
  __syncthreads();

  const int ow = tid & 63;
  const int cs = tid >> 6;   // 0..3
  const float* xb = x + (size_t)b * Cq * HWq;

  float kr[KK];
#pragma unroll
  for (int k = 0; k < KK; ++k) kr[k] = klds[k][ow];

  for (int c = cs; c < Cq; c += 4) {
    const float* xc = xb + c * HWq;
    float s = 0.f;
#pragma unroll
    for (int dy = 0; dy < 5; ++dy) {
      int ih = 2 * oh + dy - 2;
      if ((unsigned)ih < (unsigned)Hq) {
#pragma unroll
        for (int dx = 0; dx < 5; ++dx) {
          int iw = 2 * ow + dx - 2;
          float v = ((unsigned)iw < (unsigned)Wq) ? xc[ih * Wq + iw] : 0.f;
          s += v * kr[dy * 5 + dx];
        }
      }
    }
    out[(size_t)(b * Cq + c) * NHW + oh * NW + ow] = s;
  }
}

extern "C" void kernel_launch(void* const* d_in, const int* in_sizes, int n_in,
                              void* d_out, int out_size, void* d_ws, size_t ws_size,
                              hipStream_t stream) {
  const float* x  = (const float*)d_in[0];
  const float* w1 = (const float*)d_in[1];
  const float* b1 = (const float*)d_in[2];
  const float* w2 = (const float*)d_in[3];
  const float* b2 = (const float*)d_in[4];
  float* out = (float*)d_out;

  float* t1  = (float*)d_ws;                       // B*M*H*W = 8,388,608 floats
  float* ker = t1 + (size_t)Bq * Mq * HWq;         // B*25*nH*nW = 819,200 floats

  conv1x1_kernel<<<Bq * 64, 256, 0, stream>>>(x, w1, b1, t1);
  encoder_kernel<<<Bq * NH, 64, 0, stream>>>(t1, w2, b2, ker);
  reassemble_kernel<<<Bq * NH, 256, 0, stream>>>(x, ker, out);
}

// Round 4
// 443.306 us; speedup vs baseline: 1.3430x; 1.3430x over previous
//
#include <hip/hip_runtime.h>
#include <hip/hip_bf16.h>

// (B,C,H,W)=(8,256,128,128), M=64, K=5, S=2, nH=nW=64
#define Bq 8
#define Cq 256
#define Hq 128
#define Wq 128
#define Mq 64
#define KK 25
#define NH 64
#define NW 64
#define HWq (Hq*Wq)      // 16384
#define NHW (NH*NW)      // 4096

// ---------------- Kernel A: 1x1 conv (C=256 -> M=64) + bias ----------------
// 512 blocks x 256 thr. Thread = (lane pixel-group of 4, mg of 16 m).
// Each ds_read_b128 (4 weights) feeds 16 FMAs -> FMA-issue-bound.
__global__ __launch_bounds__(256) void conv1x1_kernel(
    const float* __restrict__ x, const float* __restrict__ w1,
    const float* __restrict__ b1, float* __restrict__ t1) {
  __shared__ float wlds[64 * 64];   // [c_local][m]
  const int tid  = threadIdx.x;
  const int lane = tid & 63;
  const int mg   = tid >> 6;        // 0..3, m = mg*16 + ms
  const int P0   = blockIdx.x << 8; // 256 pixels per block
  const int b    = P0 >> 14;
  const int hw0  = P0 & (HWq - 1);
  const float* xb = x + (size_t)b * Cq * HWq + hw0 + lane;

  float acc[16][4];
#pragma unroll
  for (int i = 0; i < 16; ++i)
#pragma unroll
    for (int j = 0; j < 4; ++j) acc[i][j] = 0.f;

  for (int cc = 0; cc < 4; ++cc) {
    __syncthreads();
    // stage w1[m][cc*64+cl] -> wlds[cl*64+m]; lanes vary m -> conflict-free LDS
#pragma unroll
    for (int i = 0; i < 16; ++i) {
      int cl = (tid >> 6) + i * 4;
      int m  = tid & 63;
      wlds[cl * 64 + m] = w1[m * Cq + cc * 64 + cl];
    }
    __syncthreads();
#pragma unroll 4
    for (int cl = 0; cl < 64; ++cl) {
      const float* xc = xb + (size_t)(cc * 64 + cl) * HWq;
      float xv0 = xc[0], xv1 = xc[64], xv2 = xc[128], xv3 = xc[192];
      const float4* wp = (const float4*)&wlds[cl * 64 + mg * 16];
#pragma unroll
      for (int q = 0; q < 4; ++q) {
        float4 w = wp[q];
        acc[q*4+0][0] += w.x * xv0; acc[q*4+0][1] += w.x * xv1;
        acc[q*4+0][2] += w.x * xv2; acc[q*4+0][3] += w.x * xv3;
        acc[q*4+1][0] += w.y * xv0; acc[q*4+1][1] += w.y * xv1;
        acc[q*4+1][2] += w.y * xv2; acc[q*4+1][3] += w.y * xv3;
        acc[q*4+2][0] += w.z * xv0; acc[q*4+2][1] += w.z * xv1;
        acc[q*4+2][2] += w.z * xv2; acc[q*4+2][3] += w.z * xv3;
        acc[q*4+3][0] += w.w * xv0; acc[q*4+3][1] += w.w * xv1;
        acc[q*4+3][2] += w.w * xv2; acc[q*4+3][3] += w.w * xv3;
      }
    }
  }
#pragma unroll
  for (int ms = 0; ms < 16; ++ms) {
    int m = mg * 16 + ms;
    float bv = b1[m];
    float* rp = t1 + (size_t)(b * Mq + m) * HWq + hw0 + lane;
    rp[0]   = acc[ms][0] + bv;
    rp[64]  = acc[ms][1] + bv;
    rp[128] = acc[ms][2] + bv;
    rp[192] = acc[ms][3] + bv;
  }
}

// ------- Kernel B: 3x3 s2 conv (M=64 -> 25) + bias + softmax(25) -------
// 512 blocks x 256 thr = 64 ow x 4 m-groups (16 m each); LDS partial-reduce.
#define ENC_PAD 26
__global__ __launch_bounds__(256) void encoder_kernel(
    const float* __restrict__ t1, const float* __restrict__ w2,
    const float* __restrict__ b2, float* __restrict__ ker) {
  __shared__ float sbuf[576 * ENC_PAD];   // w2t[(m*9+r)][k]; aliased as red later
  const int tid = threadIdx.x;
  const int ow  = tid & 63;
  const int mg  = tid >> 6;
  const int b   = blockIdx.x >> 6;
  const int oh  = blockIdx.x & 63;

  for (int i = tid; i < KK * 576; i += 256) {
    int mr = i / 25;
    int k  = i - mr * 25;
    sbuf[mr * ENC_PAD + k] = w2[k * 576 + mr];
  }
  __syncthreads();

  float acc[KK];
#pragma unroll
  for (int k = 0; k < KK; ++k) acc[k] = 0.f;

  const float* tb = t1 + (size_t)b * Mq * HWq;
  for (int mi = 0; mi < 16; ++mi) {
    int m = mg * 16 + mi;
    const float* tm = tb + (size_t)m * HWq;
#pragma unroll
    for (int dh = 0; dh < 3; ++dh) {
      int ih = 2 * oh + dh - 1;
      if ((unsigned)ih < (unsigned)Hq) {
        const float* tr = tm + ih * Wq;
        int iwb = 2 * ow - 1;
        float v0 = (ow > 0) ? tr[iwb] : 0.f;
        float v1 = tr[iwb + 1];
        float v2 = tr[iwb + 2];
        const float* wr = &sbuf[(m * 9 + dh * 3) * ENC_PAD];
#pragma unroll
        for (int k = 0; k < KK; ++k) acc[k] += v0 * wr[k];
#pragma unroll
        for (int k = 0; k < KK; ++k) acc[k] += v1 * wr[ENC_PAD + k];
#pragma unroll
        for (int k = 0; k < KK; ++k) acc[k] += v2 * wr[2 * ENC_PAD + k];
      }
    }
  }
  __syncthreads();                 // all w2t reads done; alias sbuf as red
  float* red = sbuf;               // red[mg][k][ow] = mg*1600 + k*64 + ow
#pragma unroll
  for (int k = 0; k < KK; ++k) red[mg * 1600 + k * 64 + ow] = acc[k];
  __syncthreads();
  if (tid < 64) {
    float lg[KK];
#pragma unroll
    for (int k = 0; k < KK; ++k)
      lg[k] = red[k * 64 + tid] + red[1600 + k * 64 + tid]
            + red[3200 + k * 64 + tid] + red[4800 + k * 64 + tid] + b2[k];
    float mx = lg[0];
#pragma unroll
    for (int k = 1; k < KK; ++k) mx = fmaxf(mx, lg[k]);
    float s = 0.f;
#pragma unroll
    for (int k = 0; k < KK; ++k) { lg[k] = __expf(lg[k] - mx); s += lg[k]; }
    float inv = 1.f / s;
    float* kb = ker + (size_t)b * KK * NHW + oh * NW + tid;
#pragma unroll
    for (int k = 0; k < KK; ++k) kb[k * NHW] = lg[k] * inv;
  }
}

// --------- Kernel C: CARAFE reassembly, 2 output rows per thread ---------
// 512 blocks = (b, oh-pair, c-half) x 256 thr = 64 ow x 4 c-subgroups.
// 7 input rows serve both output rows: 35 loads -> 50 FMAs.
__global__ __launch_bounds__(256) void reassemble_kernel(
    const float* __restrict__ x, const float* __restrict__ ker,
    float* __restrict__ out) {
  __shared__ float klds[2][KK][64];
  const int tid = threadIdx.x;
  const int bid = blockIdx.x;
  const int ch  = bid & 1;
  const int ohp = (bid >> 1) & 31;
  const int b   = bid >> 6;
  const int oh0 = 2 * ohp;

  for (int i = tid; i < 2 * KK * 64; i += 256) {
    int rr  = i / 1600;
    int rem = i - rr * 1600;
    int k   = rem >> 6;
    int owi = rem & 63;
    klds[rr][k][owi] = ker[(size_t)(b * KK + k) * NHW + (oh0 + rr) * NW + owi];
  }
  __syncthreads();

  const int ow = tid & 63;
  const int cs = tid >> 6;
  float kr0[KK], kr1[KK];
#pragma unroll
  for (int k = 0; k < KK; ++k) { kr0[k] = klds[0][k][ow]; kr1[k] = klds[1][k][ow]; }

  const int r0  = 4 * ohp - 2;
  const int iwb = 2 * ow - 2;
  const bool e0 = (iwb >= 0);       // ow > 0: columns iwb and iwb+1 in-bounds
  const bool e4 = (iwb + 4 < Wq);   // ow < 63

  for (int ci = 0; ci < 32; ++ci) {
    int c = (ch << 7) + (cs << 5) + ci;
    const float* xc = x + (size_t)(b * Cq + c) * HWq;
    float a0 = 0.f, a1 = 0.f;
#pragma unroll
    for (int j = 0; j < 7; ++j) {
      int ih = r0 + j;
      bool rok = (unsigned)ih < (unsigned)Hq;
      const float* xr = xc + ih * Wq;
      float v0 = (rok && e0) ? xr[iwb]     : 0.f;   // iw = 2*ow-2
      float v1 = (rok && e0) ? xr[iwb + 1] : 0.f;   // iw = 2*ow-1 (also <0 at ow=0!)
      float v2 = rok         ? xr[iwb + 2] : 0.f;   // iw = 2*ow   (always ok)
      float v3 = rok         ? xr[iwb + 3] : 0.f;   // iw = 2*ow+1 (<=127 ok)
      float v4 = (rok && e4) ? xr[iwb + 4] : 0.f;   // iw = 2*ow+2
      if (j < 5) {
        a0 += v0 * kr0[j*5+0]; a0 += v1 * kr0[j*5+1]; a0 += v2 * kr0[j*5+2];
        a0 += v3 * kr0[j*5+3]; a0 += v4 * kr0[j*5+4];
      }
      if (j >= 2) {
        int dy = j - 2;
        a1 += v0 * kr1[dy*5+0]; a1 += v1 * kr1[dy*5+1]; a1 += v2 * kr1[dy*5+2];
        a1 += v3 * kr1[dy*5+3]; a1 += v4 * kr1[dy*5+4];
      }
    }
    float* op = out + (size_t)(b * Cq + c) * NHW + oh0 * NW + ow;
    op[0]  = a0;
    op[NW] = a1;
  }
}

extern "C" void kernel_launch(void* const* d_in, const int* in_sizes, int n_in,
                              void* d_out, int out_size, void* d_ws, size_t ws_size,
                              hipStream_t stream) {
  const float* x  = (const float*)d_in[0];
  const float* w1 = (const float*)d_in[1];
  const float* b1 = (const float*)d_in[2];
  const float* w2 = (const float*)d_in[3];
  const float* b2 = (const float*)d_in[4];
  float* out = (float*)d_out;

  float* t1  = (float*)d_ws;                       // 8,388,608 floats
  float* ker = t1 + (size_t)Bq * Mq * HWq;         // 819,200 floats

  conv1x1_kernel<<<512, 256, 0, stream>>>(x, w1, b1, t1);
  encoder_kernel<<<Bq * NH, 256, 0, stream>>>(t1, w2, b2, ker);
  reassemble_kernel<<<512, 256, 0, stream>>>(x, ker, out);
}

// Round 5
// 321.217 us; speedup vs baseline: 1.8534x; 1.3801x over previous
//
#include <hip/hip_runtime.h>
#include <hip/hip_bf16.h>

// (B,C,H,W)=(8,256,128,128), M=64, K=5, S=2, nH=nW=64
#define Bq 8
#define Cq 256
#define Hq 128
#define Wq 128
#define Mq 64
#define KK 25
#define NH 64
#define NW 64
#define HWq (Hq*Wq)      // 16384
#define NHW (NH*NW)      // 4096

typedef __attribute__((ext_vector_type(8))) short short8;
typedef __attribute__((ext_vector_type(4))) float f32x4;

__device__ __forceinline__ unsigned short f2b(float f) {
  __hip_bfloat16 h = __float2bfloat16(f);      // RNE
  return __builtin_bit_cast(unsigned short, h);
}

// ---------------- Kernel A: 1x1 conv as bf16 MFMA GEMM ----------------
// t1[b,m,p] = sum_c w1[m,c]*x[b,c,p] + b1[m].  Block: 64 m x 128 px, K=256.
// 1024 blocks x 256 thr (4 waves; wave = 64m x 32px = 4x2 mfma tiles).
// LDS: x transposed [px][c] (bf16, +8 pad), w [m][c] (bf16, +8 pad); all frag
// reads are ds_read_b128. K-chunks of 64 c, 2 mfma K-steps per chunk.
#define XPAD 72   // 64 + 8 pad, keeps 16B alignment for b128 reads
__global__ __launch_bounds__(256) void conv1x1_mfma(
    const float* __restrict__ x, const float* __restrict__ w1,
    const float* __restrict__ b1, float* __restrict__ t1) {
  __shared__ unsigned short xs[128 * XPAD];  // [px][c] 18.4 KB
  __shared__ unsigned short ws[64 * XPAD];   // [m][c]   9.2 KB
  const int tid  = threadIdx.x;
  const int lane = tid & 63;
  const int wv   = tid >> 6;          // wave 0..3 -> px base wv*32
  const int P0   = blockIdx.x << 7;   // 128 px per block
  const int b    = P0 >> 14;
  const int hw0  = P0 & (HWq - 1);

  const int quad = lane >> 4;
  const int l15  = lane & 15;

  // staging maps
  const int sc  = tid >> 2;           // x: c index 0..63
  const int sp0 = (tid & 3) * 4;      // x: px base {0,4,8,12} (+16*i)
  const int wm  = tid >> 2;           // w: m index 0..63
  const int wc0 = (tid & 3) * 16;     // w: c base

  f32x4 acc[4][2];
#pragma unroll
  for (int mt = 0; mt < 4; ++mt)
#pragma unroll
    for (int nt = 0; nt < 2; ++nt) acc[mt][nt] = (f32x4)0.f;

  for (int cc = 0; cc < 4; ++cc) {
    __syncthreads();
    // stage x chunk: global [c][px] -> LDS [px][c], fp32 -> bf16
    const float* xgc = x + ((size_t)b * Cq + cc * 64 + sc) * HWq + hw0 + sp0;
#pragma unroll
    for (int i = 0; i < 8; ++i) {
      float4 v = *(const float4*)(xgc + i * 16);
      int px = sp0 + i * 16;
      xs[(px + 0) * XPAD + sc] = f2b(v.x);
      xs[(px + 1) * XPAD + sc] = f2b(v.y);
      xs[(px + 2) * XPAD + sc] = f2b(v.z);
      xs[(px + 3) * XPAD + sc] = f2b(v.w);
    }
    // stage w chunk: [m][c] direct
    const float* wgc = w1 + wm * Cq + cc * 64 + wc0;
#pragma unroll
    for (int u = 0; u < 4; ++u) {
      float4 v = *(const float4*)(wgc + u * 4);
      unsigned short* d = &ws[wm * XPAD + wc0 + u * 4];
      d[0] = f2b(v.x); d[1] = f2b(v.y); d[2] = f2b(v.z); d[3] = f2b(v.w);
    }
    __syncthreads();
#pragma unroll
    for (int ks = 0; ks < 2; ++ks) {
      const int c0 = ks * 32 + quad * 8;   // k = quad*8 + j
      short8 af[4], bfr[2];
#pragma unroll
      for (int mt = 0; mt < 4; ++mt)       // A[m=l15][k] from ws[m][c]
        af[mt] = *(const short8*)&ws[(mt * 16 + l15) * XPAD + c0];
#pragma unroll
      for (int nt = 0; nt < 2; ++nt)       // B[k][n=l15] from xs[px][c]
        bfr[nt] = *(const short8*)&xs[(wv * 32 + nt * 16 + l15) * XPAD + c0];
#pragma unroll
      for (int mt = 0; mt < 4; ++mt)
#pragma unroll
        for (int nt = 0; nt < 2; ++nt)
          acc[mt][nt] = __builtin_amdgcn_mfma_f32_16x16x32_bf16(
              af[mt], bfr[nt], acc[mt][nt], 0, 0, 0);
    }
  }
  // epilogue: D row m = quad*4 + r, col px = l15
#pragma unroll
  for (int mt = 0; mt < 4; ++mt) {
#pragma unroll
    for (int r = 0; r < 4; ++r) {
      int m = mt * 16 + quad * 4 + r;
      float bv = b1[m];
#pragma unroll
      for (int nt = 0; nt < 2; ++nt) {
        int px = wv * 32 + nt * 16 + l15;
        t1[((size_t)b * Mq + m) * HWq + hw0 + px] = acc[mt][nt][r] + bv;
      }
    }
  }
}

// ------- Kernel B: 3x3 s2 conv (M=64 -> 25) + bias + softmax(25) -------
// 512 blocks x 512 thr = 64 ow x 8 m-groups (8 m each); LDS partial-reduce.
#define ENC_PAD 26
__global__ __launch_bounds__(512) void encoder_kernel(
    const float* __restrict__ t1, const float* __restrict__ w2,
    const float* __restrict__ b2, float* __restrict__ ker) {
  __shared__ float sbuf[576 * ENC_PAD];   // w2t[(m*9+r)][k]; aliased as red later
  const int tid = threadIdx.x;
  const int ow  = tid & 63;
  const int mg  = tid >> 6;               // 0..7
  const int b   = blockIdx.x >> 6;
  const int oh  = blockIdx.x & 63;

  for (int i = tid; i < KK * 576; i += 512) {
    int mr = i / 25;
    int k  = i - mr * 25;
    sbuf[mr * ENC_PAD + k] = w2[k * 576 + mr];
  }
  __syncthreads();

  float acc[KK];
#pragma unroll
  for (int k = 0; k < KK; ++k) acc[k] = 0.f;

  const float* tb = t1 + (size_t)b * Mq * HWq;
  for (int mi = 0; mi < 8; ++mi) {
    int m = mg * 8 + mi;
    const float* tm = tb + (size_t)m * HWq;
#pragma unroll
    for (int dh = 0; dh < 3; ++dh) {
      int ih = 2 * oh + dh - 1;
      if ((unsigned)ih < (unsigned)Hq) {
        const float* tr = tm + ih * Wq;
        int iwb = 2 * ow - 1;
        float v0 = (ow > 0) ? tr[iwb] : 0.f;
        float v1 = tr[iwb + 1];
        float v2 = tr[iwb + 2];
        const float* wr = &sbuf[(m * 9 + dh * 3) * ENC_PAD];
#pragma unroll
        for (int k = 0; k < KK; ++k) acc[k] += v0 * wr[k];
#pragma unroll
        for (int k = 0; k < KK; ++k) acc[k] += v1 * wr[ENC_PAD + k];
#pragma unroll
        for (int k = 0; k < KK; ++k) acc[k] += v2 * wr[2 * ENC_PAD + k];
      }
    }
  }
  __syncthreads();                 // all w2t reads done; alias sbuf as red
  float* red = sbuf;               // red[mg][k][ow], 8*1600 = 12800 <= 14976
#pragma unroll
  for (int k = 0; k < KK; ++k) red[mg * 1600 + k * 64 + ow] = acc[k];
  __syncthreads();
  if (tid < 64) {
    float lg[KK];
#pragma unroll
    for (int k = 0; k < KK; ++k) {
      float s = b2[k];
#pragma unroll
      for (int g = 0; g < 8; ++g) s += red[g * 1600 + k * 64 + tid];
      lg[k] = s;
    }
    float mx = lg[0];
#pragma unroll
    for (int k = 1; k < KK; ++k) mx = fmaxf(mx, lg[k]);
    float s = 0.f;
#pragma unroll
    for (int k = 0; k < KK; ++k) { lg[k] = __expf(lg[k] - mx); s += lg[k]; }
    float inv = 1.f / s;
    float* kb = ker + (size_t)b * KK * NHW + oh * NW + tid;
#pragma unroll
    for (int k = 0; k < KK; ++k) kb[k * NHW] = lg[k] * inv;
  }
}

// --------- Kernel C: CARAFE reassembly, 2 output rows per thread ---------
// 2048 blocks = (b, ohp 32, c-eighth 8) x 256 thr = 64 ow x 4 cs; 8 c/thread.
// 7 input rows serve both output rows; float2-vectorized taps.
__global__ __launch_bounds__(256) void reassemble_kernel(
    const float* __restrict__ x, const float* __restrict__ ker,
    float* __restrict__ out) {
  __shared__ float klds[2][KK][64];
  const int tid = threadIdx.x;
  const int bid = blockIdx.x;
  const int c8  = bid & 7;
  const int ohp = (bid >> 3) & 31;
  const int b   = bid >> 8;
  const int oh0 = 2 * ohp;

  for (int i = tid; i < 2 * KK * 64; i += 256) {
    int rr  = i / 1600;
    int rem = i - rr * 1600;
    int k   = rem >> 6;
    int owi = rem & 63;
    klds[rr][k][owi] = ker[(size_t)(b * KK + k) * NHW + (oh0 + rr) * NW + owi];
  }
  __syncthreads();

  const int ow = tid & 63;
  const int cs = tid >> 6;
  float kr0[KK], kr1[KK];
#pragma unroll
  for (int k = 0; k < KK; ++k) { kr0[k] = klds[0][k][ow]; kr1[k] = klds[1][k][ow]; }

  const int r0  = 4 * ohp - 2;
  const int iwb = 2 * ow - 2;
  const bool e0 = (iwb >= 0);       // ow > 0
  const bool e4 = (iwb + 4 < Wq);   // ow < 63
  const float2 z2 = make_float2(0.f, 0.f);

  for (int ci = 0; ci < 8; ++ci) {
    int c = c8 * 32 + cs * 8 + ci;
    const float* xc = x + (size_t)(b * Cq + c) * HWq;
    float a0 = 0.f, a1 = 0.f;
#pragma unroll
    for (int j = 0; j < 7; ++j) {
      int ih = r0 + j;
      bool rok = (unsigned)ih < (unsigned)Hq;
      const float* xr = xc + ih * Wq;
      float2 v01 = (rok && e0) ? *(const float2*)(xr + iwb)     : z2;  // iw-2,iw-1
      float2 v23 = rok         ? *(const float2*)(xr + iwb + 2) : z2;  // iw, iw+1
      float  v4  = (rok && e4) ? xr[iwb + 4] : 0.f;                    // iw+2
      if (j < 5) {
        a0 += v01.x * kr0[j*5+0]; a0 += v01.y * kr0[j*5+1];
        a0 += v23.x * kr0[j*5+2]; a0 += v23.y * kr0[j*5+3];
        a0 += v4    * kr0[j*5+4];
      }
      if (j >= 2) {
        int dy = j - 2;
        a1 += v01.x * kr1[dy*5+0]; a1 += v01.y * kr1[dy*5+1];
        a1 += v23.x * kr1[dy*5+2]; a1 += v23.y * kr1[dy*5+3];
        a1 += v4    * kr1[dy*5+4];
      }
    }
    float* op = out + (size_t)(b * Cq + c) * NHW + oh0 * NW + ow;
    op[0]  = a0;
    op[NW] = a1;
  }
}

extern "C" void kernel_launch(void* const* d_in, const int* in_sizes, int n_in,
                              void* d_out, int out_size, void* d_ws, size_t ws_size,
                              hipStream_t stream) {
  const float* x  = (const float*)d_in[0];
  const float* w1 = (const float*)d_in[1];
  const float* b1 = (const float*)d_in[2];
  const float* w2 = (const float*)d_in[3];
  const float* b2 = (const float*)d_in[4];
  float* out = (float*)d_out;

  float* t1  = (float*)d_ws;                       // 8,388,608 floats
  float* ker = t1 + (size_t)Bq * Mq * HWq;         // 819,200 floats

  conv1x1_mfma<<<1024, 256, 0, stream>>>(x, w1, b1, t1);
  encoder_kernel<<<Bq * NH, 512, 0, stream>>>(t1, w2, b2, ker);
  reassemble_kernel<<<2048, 256, 0, stream>>>(x, ker, out);
}

// Round 6
// 314.988 us; speedup vs baseline: 1.8901x; 1.0198x over previous
//
#include <hip/hip_runtime.h>
#include <hip/hip_bf16.h>

// (B,C,H,W)=(8,256,128,128), M=64, K=5, S=2, nH=nW=64
#define Bq 8
#define Cq 256
#define Hq 128
#define Wq 128
#define Mq 64
#define KK 25
#define NH 64
#define NW 64
#define HWq (Hq*Wq)      // 16384
#define NHW (NH*NW)      // 4096

typedef __attribute__((ext_vector_type(8))) short short8;
typedef __attribute__((ext_vector_type(4))) float f32x4;

__device__ __forceinline__ unsigned short f2b(float f) {
  __hip_bfloat16 h = __float2bfloat16(f);      // RNE
  return __builtin_bit_cast(unsigned short, h);
}

// ---------------- Kernel A: 1x1 conv as bf16 MFMA GEMM ----------------
// (unchanged from round 5)
#define XPAD 72   // 64 + 8 pad, keeps 16B alignment for b128 reads
__global__ __launch_bounds__(256) void conv1x1_mfma(
    const float* __restrict__ x, const float* __restrict__ w1,
    const float* __restrict__ b1, float* __restrict__ t1) {
  __shared__ unsigned short xs[128 * XPAD];  // [px][c] 18.4 KB
  __shared__ unsigned short ws[64 * XPAD];   // [m][c]   9.2 KB
  const int tid  = threadIdx.x;
  const int lane = tid & 63;
  const int wv   = tid >> 6;          // wave 0..3 -> px base wv*32
  const int P0   = blockIdx.x << 7;   // 128 px per block
  const int b    = P0 >> 14;
  const int hw0  = P0 & (HWq - 1);

  const int quad = lane >> 4;
  const int l15  = lane & 15;

  // staging maps
  const int sc  = tid >> 2;           // x: c index 0..63
  const int sp0 = (tid & 3) * 4;      // x: px base {0,4,8,12} (+16*i)
  const int wm  = tid >> 2;           // w: m index 0..63
  const int wc0 = (tid & 3) * 16;     // w: c base

  f32x4 acc[4][2];
#pragma unroll
  for (int mt = 0; mt < 4; ++mt)
#pragma unroll
    for (int nt = 0; nt < 2; ++nt) acc[mt][nt] = (f32x4)0.f;

  for (int cc = 0; cc < 4; ++cc) {
    __syncthreads();
    // stage x chunk: global [c][px] -> LDS [px][c], fp32 -> bf16
    const float* xgc = x + ((size_t)b * Cq + cc * 64 + sc) * HWq + hw0 + sp0;
#pragma unroll
    for (int i = 0; i < 8; ++i) {
      float4 v = *(const float4*)(xgc + i * 16);
      int px = sp0 + i * 16;
      xs[(px + 0) * XPAD + sc] = f2b(v.x);
      xs[(px + 1) * XPAD + sc] = f2b(v.y);
      xs[(px + 2) * XPAD + sc] = f2b(v.z);
      xs[(px + 3) * XPAD + sc] = f2b(v.w);
    }
    // stage w chunk: [m][c] direct
    const float* wgc = w1 + wm * Cq + cc * 64 + wc0;
#pragma unroll
    for (int u = 0; u < 4; ++u) {
      float4 v = *(const float4*)(wgc + u * 4);
      unsigned short* d = &ws[wm * XPAD + wc0 + u * 4];
      d[0] = f2b(v.x); d[1] = f2b(v.y); d[2] = f2b(v.z); d[3] = f2b(v.w);
    }
    __syncthreads();
#pragma unroll
    for (int ks = 0; ks < 2; ++ks) {
      const int c0 = ks * 32 + quad * 8;   // k = quad*8 + j
      short8 af[4], bfr[2];
#pragma unroll
      for (int mt = 0; mt < 4; ++mt)       // A[m=l15][k] from ws[m][c]
        af[mt] = *(const short8*)&ws[(mt * 16 + l15) * XPAD + c0];
#pragma unroll
      for (int nt = 0; nt < 2; ++nt)       // B[k][n=l15] from xs[px][c]
        bfr[nt] = *(const short8*)&xs[(wv * 32 + nt * 16 + l15) * XPAD + c0];
#pragma unroll
      for (int mt = 0; mt < 4; ++mt)
#pragma unroll
        for (int nt = 0; nt < 2; ++nt)
          acc[mt][nt] = __builtin_amdgcn_mfma_f32_16x16x32_bf16(
              af[mt], bfr[nt], acc[mt][nt], 0, 0, 0);
    }
  }
  // epilogue: D row m = quad*4 + r, col px = l15
#pragma unroll
  for (int mt = 0; mt < 4; ++mt) {
#pragma unroll
    for (int r = 0; r < 4; ++r) {
      int m = mt * 16 + quad * 4 + r;
      float bv = b1[m];
#pragma unroll
      for (int nt = 0; nt < 2; ++nt) {
        int px = wv * 32 + nt * 16 + l15;
        t1[((size_t)b * Mq + m) * HWq + hw0 + px] = acc[mt][nt][r] + bv;
      }
    }
  }
}

// ------- Kernel B: 3x3 s2 conv (M=64 -> 25) + bias + softmax(25) -------
// v3: weights read via SCALAR loads (wave-uniform index) -> no LDS in the
// hot loop. 512 blocks x 512 thr = 64 ow x 8 wave-aligned m-groups (8 m).
__global__ __launch_bounds__(512) void encoder_kernel(
    const float* __restrict__ t1, const float* __restrict__ w2,
    const float* __restrict__ b2, float* __restrict__ ker) {
  __shared__ float red[8][KK][64];   // 51.2 KB, reduction only
  const int tid = threadIdx.x;
  const int ow  = tid & 63;
  const int mg  = tid >> 6;          // wave index 0..7 -> 8 m per wave
  const int b   = blockIdx.x >> 6;
  const int oh  = blockIdx.x & 63;

  float acc[KK];
#pragma unroll
  for (int k = 0; k < KK; ++k) acc[k] = 0.f;

  const float* tb = t1 + (size_t)b * Mq * HWq;
  const int iwb = 2 * ow - 1;

  for (int mi = 0; mi < 8; ++mi) {
    // m is wave-uniform; pin it to an SGPR so w2 indexing stays scalar
    const int m = __builtin_amdgcn_readfirstlane(mg * 8 + mi);
    const float* tm = tb + (size_t)m * HWq;
    const float* wm = w2 + m * 9;    // w2[k*576 + m*9 + dh*3 + dw]
#pragma unroll
    for (int dh = 0; dh < 3; ++dh) {
      int ih = 2 * oh + dh - 1;
      if ((unsigned)ih < (unsigned)Hq) {
        const float* tr = tm + ih * Wq;
        float v0 = (ow > 0) ? tr[iwb] : 0.f;
        float v1 = tr[iwb + 1];
        float v2 = tr[iwb + 2];
        const float* wr = wm + dh * 3;   // uniform base
#pragma unroll
        for (int k = 0; k < KK; ++k) {
          acc[k] += v0 * wr[k * 576 + 0];
          acc[k] += v1 * wr[k * 576 + 1];
          acc[k] += v2 * wr[k * 576 + 2];
        }
      }
    }
  }
#pragma unroll
  for (int k = 0; k < KK; ++k) red[mg][k][ow] = acc[k];
  __syncthreads();
  if (tid < 64) {
    float lg[KK];
#pragma unroll
    for (int k = 0; k < KK; ++k) {
      float s = b2[k];
#pragma unroll
      for (int g = 0; g < 8; ++g) s += red[g][k][tid];
      lg[k] = s;
    }
    float mx = lg[0];
#pragma unroll
    for (int k = 1; k < KK; ++k) mx = fmaxf(mx, lg[k]);
    float s = 0.f;
#pragma unroll
    for (int k = 0; k < KK; ++k) { lg[k] = __expf(lg[k] - mx); s += lg[k]; }
    float inv = 1.f / s;
    float* kb = ker + (size_t)b * KK * NHW + oh * NW + tid;
#pragma unroll
    for (int k = 0; k < KK; ++k) kb[k * NHW] = lg[k] * inv;
  }
}

// --------- Kernel C: CARAFE reassembly, 2 output rows per thread ---------
// (unchanged from round 5)
__global__ __launch_bounds__(256) void reassemble_kernel(
    const float* __restrict__ x, const float* __restrict__ ker,
    float* __restrict__ out) {
  __shared__ float klds[2][KK][64];
  const int tid = threadIdx.x;
  const int bid = blockIdx.x;
  const int c8  = bid & 7;
  const int ohp = (bid >> 3) & 31;
  const int b   = bid >> 8;
  const int oh0 = 2 * ohp;

  for (int i = tid; i < 2 * KK * 64; i += 256) {
    int rr  = i / 1600;
    int rem = i - rr * 1600;
    int k   = rem >> 6;
    int owi = rem & 63;
    klds[rr][k][owi] = ker[(size_t)(b * KK + k) * NHW + (oh0 + rr) * NW + owi];
  }
  __syncthreads();

  const int ow = tid & 63;
  const int cs = tid >> 6;
  float kr0[KK], kr1[KK];
#pragma unroll
  for (int k = 0; k < KK; ++k) { kr0[k] = klds[0][k][ow]; kr1[k] = klds[1][k][ow]; }

  const int r0  = 4 * ohp - 2;
  const int iwb = 2 * ow - 2;
  const bool e0 = (iwb >= 0);       // ow > 0
  const bool e4 = (iwb + 4 < Wq);   // ow < 63
  const float2 z2 = make_float2(0.f, 0.f);

  for (int ci = 0; ci < 8; ++ci) {
    int c = c8 * 32 + cs * 8 + ci;
    const float* xc = x + (size_t)(b * Cq + c) * HWq;
    float a0 = 0.f, a1 = 0.f;
#pragma unroll
    for (int j = 0; j < 7; ++j) {
      int ih = r0 + j;
      bool rok = (unsigned)ih < (unsigned)Hq;
      const float* xr = xc + ih * Wq;
      float2 v01 = (rok && e0) ? *(const float2*)(xr + iwb)     : z2;  // iw-2,iw-1
      float2 v23 = rok         ? *(const float2*)(xr + iwb + 2) : z2;  // iw, iw+1
      float  v4  = (rok && e4) ? xr[iwb + 4] : 0.f;                    // iw+2
      if (j < 5) {
        a0 += v01.x * kr0[j*5+0]; a0 += v01.y * kr0[j*5+1];
        a0 += v23.x * kr0[j*5+2]; a0 += v23.y * kr0[j*5+3];
        a0 += v4    * kr0[j*5+4];
      }
      if (j >= 2) {
        int dy = j - 2;
        a1 += v01.x * kr1[dy*5+0]; a1 += v01.y * kr1[dy*5+1];
        a1 += v23.x * kr1[dy*5+2]; a1 += v23.y * kr1[dy*5+3];
        a1 += v4    * kr1[dy*5+4];
      }
    }
    float* op = out + (size_t)(b * Cq + c) * NHW + oh0 * NW + ow;
    op[0]  = a0;
    op[NW] = a1;
  }
}

extern "C" void kernel_launch(void* const* d_in, const int* in_sizes, int n_in,
                              void* d_out, int out_size, void* d_ws, size_t ws_size,
                              hipStream_t stream) {
  const float* x  = (const float*)d_in[0];
  const float* w1 = (const float*)d_in[1];
  const float* b1 = (const float*)d_in[2];
  const float* w2 = (const float*)d_in[3];
  const float* b2 = (const float*)d_in[4];
  float* out = (float*)d_out;

  float* t1  = (float*)d_ws;                       // 8,388,608 floats
  float* ker = t1 + (size_t)Bq * Mq * HWq;         // 819,200 floats

  conv1x1_mfma<<<1024, 256, 0, stream>>>(x, w1, b1, t1);
  encoder_kernel<<<Bq * NH, 512, 0, stream>>>(t1, w2, b2, ker);
  reassemble_kernel<<<2048, 256, 0, stream>>>(x, ker, out);
}

// Round 7
// 301.416 us; speedup vs baseline: 1.9752x; 1.0450x over previous
//
#include <hip/hip_runtime.h>
#include <hip/hip_bf16.h>

// (B,C,H,W)=(8,256,128,128), M=64, K=5, S=2, nH=nW=64
#define Bq 8
#define Cq 256
#define Hq 128
#define Wq 128
#define Mq 64
#define KK 25
#define NH 64
#define NW 64
#define HWq (Hq*Wq)      // 16384
#define NHW (NH*NW)      // 4096

typedef __attribute__((ext_vector_type(8))) short short8;
typedef __attribute__((ext_vector_type(4))) float f32x4;

__device__ __forceinline__ unsigned short f2b(float f) {
  __hip_bfloat16 h = __float2bfloat16(f);      // RNE
  return __builtin_bit_cast(unsigned short, h);
}

// ---------------- Kernel A: 1x1 conv as bf16 MFMA GEMM ----------------
// (unchanged from round 6)
#define XPAD 72   // 64 + 8 pad, keeps 16B alignment for b128 reads
__global__ __launch_bounds__(256) void conv1x1_mfma(
    const float* __restrict__ x, const float* __restrict__ w1,
    const float* __restrict__ b1, float* __restrict__ t1) {
  __shared__ unsigned short xs[128 * XPAD];  // [px][c] 18.4 KB
  __shared__ unsigned short ws[64 * XPAD];   // [m][c]   9.2 KB
  const int tid  = threadIdx.x;
  const int lane = tid & 63;
  const int wv   = tid >> 6;          // wave 0..3 -> px base wv*32
  const int P0   = blockIdx.x << 7;   // 128 px per block
  const int b    = P0 >> 14;
  const int hw0  = P0 & (HWq - 1);

  const int quad = lane >> 4;
  const int l15  = lane & 15;

  // staging maps
  const int sc  = tid >> 2;           // x: c index 0..63
  const int sp0 = (tid & 3) * 4;      // x: px base {0,4,8,12} (+16*i)
  const int wm  = tid >> 2;           // w: m index 0..63
  const int wc0 = (tid & 3) * 16;     // w: c base

  f32x4 acc[4][2];
#pragma unroll
  for (int mt = 0; mt < 4; ++mt)
#pragma unroll
    for (int nt = 0; nt < 2; ++nt) acc[mt][nt] = (f32x4)0.f;

  for (int cc = 0; cc < 4; ++cc) {
    __syncthreads();
    // stage x chunk: global [c][px] -> LDS [px][c], fp32 -> bf16
    const float* xgc = x + ((size_t)b * Cq + cc * 64 + sc) * HWq + hw0 + sp0;
#pragma unroll
    for (int i = 0; i < 8; ++i) {
      float4 v = *(const float4*)(xgc + i * 16);
      int px = sp0 + i * 16;
      xs[(px + 0) * XPAD + sc] = f2b(v.x);
      xs[(px + 1) * XPAD + sc] = f2b(v.y);
      xs[(px + 2) * XPAD + sc] = f2b(v.z);
      xs[(px + 3) * XPAD + sc] = f2b(v.w);
    }
    // stage w chunk: [m][c] direct
    const float* wgc = w1 + wm * Cq + cc * 64 + wc0;
#pragma unroll
    for (int u = 0; u < 4; ++u) {
      float4 v = *(const float4*)(wgc + u * 4);
      unsigned short* d = &ws[wm * XPAD + wc0 + u * 4];
      d[0] = f2b(v.x); d[1] = f2b(v.y); d[2] = f2b(v.z); d[3] = f2b(v.w);
    }
    __syncthreads();
#pragma unroll
    for (int ks = 0; ks < 2; ++ks) {
      const int c0 = ks * 32 + quad * 8;   // k = quad*8 + j
      short8 af[4], bfr[2];
#pragma unroll
      for (int mt = 0; mt < 4; ++mt)       // A[m=l15][k] from ws[m][c]
        af[mt] = *(const short8*)&ws[(mt * 16 + l15) * XPAD + c0];
#pragma unroll
      for (int nt = 0; nt < 2; ++nt)       // B[k][n=l15] from xs[px][c]
        bfr[nt] = *(const short8*)&xs[(wv * 32 + nt * 16 + l15) * XPAD + c0];
#pragma unroll
      for (int mt = 0; mt < 4; ++mt)
#pragma unroll
        for (int nt = 0; nt < 2; ++nt)
          acc[mt][nt] = __builtin_amdgcn_mfma_f32_16x16x32_bf16(
              af[mt], bfr[nt], acc[mt][nt], 0, 0, 0);
    }
  }
  // epilogue: D row m = quad*4 + r, col px = l15
#pragma unroll
  for (int mt = 0; mt < 4; ++mt) {
#pragma unroll
    for (int r = 0; r < 4; ++r) {
      int m = mt * 16 + quad * 4 + r;
      float bv = b1[m];
#pragma unroll
      for (int nt = 0; nt < 2; ++nt) {
        int px = wv * 32 + nt * 16 + l15;
        t1[((size_t)b * Mq + m) * HWq + hw0 + px] = acc[mt][nt][r] + bv;
      }
    }
  }
}

// ------- Kernel B: 3x3 s2 conv (M=64 -> 25) + bias + softmax(25) -------
// (unchanged from round 6: scalar weight loads, LDS only for reduction)
__global__ __launch_bounds__(512) void encoder_kernel(
    const float* __restrict__ t1, const float* __restrict__ w2,
    const float* __restrict__ b2, float* __restrict__ ker) {
  __shared__ float red[8][KK][64];   // 51.2 KB, reduction only
  const int tid = threadIdx.x;
  const int ow  = tid & 63;
  const int mg  = tid >> 6;          // wave index 0..7 -> 8 m per wave
  const int b   = blockIdx.x >> 6;
  const int oh  = blockIdx.x & 63;

  float acc[KK];
#pragma unroll
  for (int k = 0; k < KK; ++k) acc[k] = 0.f;

  const float* tb = t1 + (size_t)b * Mq * HWq;
  const int iwb = 2 * ow - 1;

  for (int mi = 0; mi < 8; ++mi) {
    const int m = __builtin_amdgcn_readfirstlane(mg * 8 + mi);
    const float* tm = tb + (size_t)m * HWq;
    const float* wm = w2 + m * 9;    // w2[k*576 + m*9 + dh*3 + dw]
#pragma unroll
    for (int dh = 0; dh < 3; ++dh) {
      int ih = 2 * oh + dh - 1;
      if ((unsigned)ih < (unsigned)Hq) {
        const float* tr = tm + ih * Wq;
        float v0 = (ow > 0) ? tr[iwb] : 0.f;
        float v1 = tr[iwb + 1];
        float v2 = tr[iwb + 2];
        const float* wr = wm + dh * 3;   // uniform base
#pragma unroll
        for (int k = 0; k < KK; ++k) {
          acc[k] += v0 * wr[k * 576 + 0];
          acc[k] += v1 * wr[k * 576 + 1];
          acc[k] += v2 * wr[k * 576 + 2];
        }
      }
    }
  }
#pragma unroll
  for (int k = 0; k < KK; ++k) red[mg][k][ow] = acc[k];
  __syncthreads();
  if (tid < 64) {
    float lg[KK];
#pragma unroll
    for (int k = 0; k < KK; ++k) {
      float s = b2[k];
#pragma unroll
      for (int g = 0; g < 8; ++g) s += red[g][k][tid];
      lg[k] = s;
    }
    float mx = lg[0];
#pragma unroll
    for (int k = 1; k < KK; ++k) mx = fmaxf(mx, lg[k]);
    float s = 0.f;
#pragma unroll
    for (int k = 0; k < KK; ++k) { lg[k] = __expf(lg[k] - mx); s += lg[k]; }
    float inv = 1.f / s;
    float* kb = ker + (size_t)b * KK * NHW + oh * NW + tid;
#pragma unroll
    for (int k = 0; k < KK; ++k) kb[k * NHW] = lg[k] * inv;
  }
}

// --------- Kernel C: CARAFE reassembly, LDS x-slab version ---------
// Block = (b, ohg of 8 out-rows, cg of 8 channels): 2048 blocks x 256 thr.
// Stage 19 input rows x 128 px x 8 c (76 KB) in LDS once; compute reads LDS
// (25-cyc) instead of L2 (200-cyc). Border rows pre-zeroed -> no row guard.
#define RSL_ROWS 19
#define RSL_CSZ  (RSL_ROWS * Wq)      // 2432 floats per channel slab
__global__ __launch_bounds__(256) void reassemble_kernel(
    const float* __restrict__ x, const float* __restrict__ ker,
    float* __restrict__ out) {
  __shared__ float xsl[8 * RSL_CSZ + 8];   // 76 KB + pad
  const int tid = threadIdx.x;
  const int bid = blockIdx.x;
  const int cg  = bid & 31;
  const int ohg = (bid >> 5) & 7;
  const int b   = bid >> 8;
  const int r0  = 16 * ohg - 2;            // first slab row = x row r0

  // zero out-of-bounds border rows (ohg==0: slab rows 0..1; ohg==7: row 18)
  const int zlo = (r0 < 0) ? -r0 : 0;
  const int zhi = (r0 + RSL_ROWS > Hq) ? (r0 + RSL_ROWS - Hq) : 0;
  if (zlo > 0) {
    for (int c = 0; c < 8; ++c)
      for (int i = tid; i < zlo * Wq; i += 256) xsl[c * RSL_CSZ + i] = 0.f;
  }
  if (zhi > 0) {
    for (int c = 0; c < 8; ++c)
      for (int i = tid; i < zhi * Wq; i += 256)
        xsl[c * RSL_CSZ + (RSL_ROWS - zhi) * Wq + i] = 0.f;
  }
  // stage valid rows: contiguous [vs,ve) rows per channel, float4 coalesced
  const int vs = (r0 > 0) ? r0 : 0;
  const int ve = (r0 + RSL_ROWS < Hq) ? (r0 + RSL_ROWS) : Hq;
  const int nvec = ((ve - vs) * Wq) >> 2;          // float4 count
  const int loff = (vs - r0) * Wq;
  for (int c = 0; c < 8; ++c) {
    const float* g = x + ((size_t)(b * Cq + cg * 8 + c)) * HWq + vs * Wq;
    float* d = xsl + c * RSL_CSZ + loff;
    for (int i = tid; i < nvec; i += 256) {
      float4 v = *(const float4*)(g + 4 * i);
      *(float4*)(d + 4 * i) = v;
    }
  }

  // per-thread ker weights (read while staging loads are in flight is fine)
  const int ow = tid & 63;
  const int rq = tid >> 6;                 // 0..3 -> out rows oh, oh+1
  const int oh = 8 * ohg + 2 * rq;
  float kr0[KK], kr1[KK];
  const float* kb = ker + (size_t)b * KK * NHW + oh * NW + ow;
#pragma unroll
  for (int k = 0; k < KK; ++k) { kr0[k] = kb[k * NHW]; kr1[k] = kb[k * NHW + NW]; }

  __syncthreads();

  const int jb = 4 * rq;                   // slab row base for this thread
  const bool e0 = (ow > 0);
  const bool e4 = (ow < 63);
  const float2 z2 = make_float2(0.f, 0.f);

  for (int c = 0; c < 8; ++c) {
    const float* sl = xsl + c * RSL_CSZ;
    float a0 = 0.f, a1 = 0.f;
#pragma unroll
    for (int j = 0; j < 7; ++j) {
      const float* xr = sl + (jb + j) * Wq + 2 * ow - 2;
      float2 v01 = e0 ? *(const float2*)xr : z2;        // taps -2,-1
      float2 v23 = *(const float2*)(xr + 2);            // taps  0,+1
      float  v4  = e4 ? xr[4] : 0.f;                    // tap  +2
      if (j < 5) {
        a0 += v01.x * kr0[j*5+0]; a0 += v01.y * kr0[j*5+1];
        a0 += v23.x * kr0[j*5+2]; a0 += v23.y * kr0[j*5+3];
        a0 += v4    * kr0[j*5+4];
      }
      if (j >= 2) {
        int dy = j - 2;
        a1 += v01.x * kr1[dy*5+0]; a1 += v01.y * kr1[dy*5+1];
        a1 += v23.x * kr1[dy*5+2]; a1 += v23.y * kr1[dy*5+3];
        a1 += v4    * kr1[dy*5+4];
      }
    }
    float* op = out + ((size_t)(b * Cq + cg * 8 + c)) * NHW + oh * NW + ow;
    op[0]  = a0;
    op[NW] = a1;
  }
}

extern "C" void kernel_launch(void* const* d_in, const int* in_sizes, int n_in,
                              void* d_out, int out_size, void* d_ws, size_t ws_size,
                              hipStream_t stream) {
  const float* x  = (const float*)d_in[0];
  const float* w1 = (const float*)d_in[1];
  const float* b1 = (const float*)d_in[2];
  const float* w2 = (const float*)d_in[3];
  const float* b2 = (const float*)d_in[4];
  float* out = (float*)d_out;

  float* t1  = (float*)d_ws;                       // 8,388,608 floats
  float* ker = t1 + (size_t)Bq * Mq * HWq;         // 819,200 floats

  conv1x1_mfma<<<1024, 256, 0, stream>>>(x, w1, b1, t1);
  encoder_kernel<<<Bq * NH, 512, 0, stream>>>(t1, w2, b2, ker);
  reassemble_kernel<<<2048, 256, 0, stream>>>(x, ker, out);
}

// Round 8
// 298.256 us; speedup vs baseline: 1.9961x; 1.0106x over previous
//
#include <hip/hip_runtime.h>
#include <hip/hip_bf16.h>

// (B,C,H,W)=(8,256,128,128), M=64, K=5, S=2, nH=nW=64
#define Bq 8
#define Cq 256
#define Hq 128
#define Wq 128
#define Mq 64
#define KK 25
#define NH 64
#define NW 64
#define HWq (Hq*Wq)      // 16384
#define NHW (NH*NW)      // 4096

typedef __attribute__((ext_vector_type(8))) short short8;
typedef __attribute__((ext_vector_type(4))) float f32x4;

__device__ __forceinline__ unsigned short f2b(float f) {
  __hip_bfloat16 h = __float2bfloat16(f);      // RNE
  return __builtin_bit_cast(unsigned short, h);
}
__device__ __forceinline__ unsigned int pk2(float a, float b) {
  return (unsigned int)f2b(a) | ((unsigned int)f2b(b) << 16);
}

// ---------------- Kernel A: 1x1 conv as bf16 MFMA GEMM, barrier-free K-loop --
// t1[b,m,p] = sum_c w1[m,c]*x[b,c,p] + b1[m].  Block: 64 m x 128 px, K=256.
// 1024 blocks x 256 thr. Weights staged to LDS ONCE (single barrier); each
// wave owns a private double-buffered 32-px x-tile in LDS -> no __syncthreads
// in the K-loop; 1-deep SW pipeline keeps VMEM queue full.
// ws stride 280 shorts (140 dw = 12 mod 32 -> 2-way bank alias, free);
// xs stride 80 shorts (40 dw = 8 mod 32 -> 4-way on 16 bfr reads, minor).
#define WS_STR 280
#define XS_STR 80
__global__ __launch_bounds__(256) void conv1x1_mfma(
    const float* __restrict__ x, const float* __restrict__ w1,
    const float* __restrict__ b1, float* __restrict__ t1) {
  __shared__ unsigned short wsl[64 * WS_STR];        // 35.8 KB  [m][c]
  __shared__ unsigned short xsl[2][4][32 * XS_STR];  // 41.0 KB  [buf][wave][px][c]
  const int tid  = threadIdx.x;
  const int lane = tid & 63;
  const int wv   = tid >> 6;          // wave 0..3 -> px base wv*32
  const int P0   = blockIdx.x << 7;   // 128 px per block
  const int b    = P0 >> 14;
  const int hw0  = P0 & (HWq - 1);

  const int quad = lane >> 4;
  const int l15  = lane & 15;

  // ---- stage ALL weights once: w1[m][c] fp32 -> wsl[m][c] bf16 (packed) ----
  {
    const int m  = tid >> 2;
    const int cb = (tid & 3) * 64;
    const float* wg = w1 + m * Cq + cb;
    unsigned int* wu = (unsigned int*)&wsl[m * WS_STR + cb];
#pragma unroll
    for (int u = 0; u < 16; ++u) {
      float4 v = *(const float4*)(wg + 4 * u);
      wu[2 * u]     = pk2(v.x, v.y);
      wu[2 * u + 1] = pk2(v.z, v.w);
    }
  }
  __syncthreads();   // the only block barrier before epilogue

  // ---- per-wave x staging maps: lane = (cp 0..31, pg 0..1) ----
  const int cp = lane >> 1;           // channel pair -> c = 2*cp, 2*cp+1
  const int pg = lane & 1;            // px half: 16 px
  const float* xb = x + (size_t)b * Cq * HWq + hw0 + wv * 32 + pg * 16;
  unsigned int* xu = (unsigned int*)&xsl[0][0][0];   // index = buf*4*1280 + wv*1280 + px*40 + cp

  f32x4 acc[4][2];
#pragma unroll
  for (int mt = 0; mt < 4; ++mt)
#pragma unroll
    for (int nt = 0; nt < 2; ++nt) acc[mt][nt] = (f32x4)0.f;

  float4 cur[8];
  // load chunk 0 (channels 2cp, 2cp+1 of chunk): 8 float4 = 32 px total
  {
    const float* g = xb + (size_t)(2 * cp) * HWq;
#pragma unroll
    for (int u = 0; u < 4; ++u) cur[u]     = *(const float4*)(g + 4 * u);
#pragma unroll
    for (int u = 0; u < 4; ++u) cur[4 + u] = *(const float4*)(g + HWq + 4 * u);
  }

  for (int cc = 0; cc < 4; ++cc) {
    // ---- store chunk cc into buf[cc&1] (cvt + packed b32 writes) ----
    {
      unsigned int* d = xu + ((cc & 1) * 4 + wv) * 1280 + cp;
#pragma unroll
      for (int u = 0; u < 4; ++u) {
        int px0 = pg * 16 + 4 * u;
        d[(px0 + 0) * 40] = pk2(cur[u].x, cur[4 + u].x);
        d[(px0 + 1) * 40] = pk2(cur[u].y, cur[4 + u].y);
        d[(px0 + 2) * 40] = pk2(cur[u].z, cur[4 + u].z);
        d[(px0 + 3) * 40] = pk2(cur[u].w, cur[4 + u].w);
      }
    }
    // ---- issue loads for chunk cc+1 (in flight during MFMA below) ----
    if (cc < 3) {
      const float* g = xb + (size_t)((cc + 1) * 64 + 2 * cp) * HWq;
#pragma unroll
      for (int u = 0; u < 4; ++u) cur[u]     = *(const float4*)(g + 4 * u);
#pragma unroll
      for (int u = 0; u < 4; ++u) cur[4 + u] = *(const float4*)(g + HWq + 4 * u);
    }
    // ---- compute chunk cc from buf[cc&1] ----
    const unsigned short* xw = &xsl[cc & 1][wv][0];
#pragma unroll
    for (int ks = 0; ks < 2; ++ks) {
      const int c0 = ks * 32 + quad * 8;       // k offset within chunk
      short8 af[4], bfr[2];
#pragma unroll
      for (int mt = 0; mt < 4; ++mt)           // A[m=l15][k] from wsl[m][c]
        af[mt] = *(const short8*)&wsl[(mt * 16 + l15) * WS_STR + cc * 64 + c0];
#pragma unroll
      for (int nt = 0; nt < 2; ++nt)           // B[k][n=l15] from xsl[px][c]
        bfr[nt] = *(const short8*)&xw[(nt * 16 + l15) * XS_STR + c0];
#pragma unroll
      for (int mt = 0; mt < 4; ++mt)
#pragma unroll
        for (int nt = 0; nt < 2; ++nt)
          acc[mt][nt] = __builtin_amdgcn_mfma_f32_16x16x32_bf16(
              af[mt], bfr[nt], acc[mt][nt], 0, 0, 0);
    }
  }

  // epilogue: D row m = quad*4 + r, col px = l15
#pragma unroll
  for (int mt = 0; mt < 4; ++mt) {
#pragma unroll
    for (int r = 0; r < 4; ++r) {
      int m = mt * 16 + quad * 4 + r;
      float bv = b1[m];
#pragma unroll
      for (int nt = 0; nt < 2; ++nt) {
        int px = wv * 32 + nt * 16 + l15;
        t1[((size_t)b * Mq + m) * HWq + hw0 + px] = acc[mt][nt][r] + bv;
      }
    }
  }
}

// ------- Kernel B: 3x3 s2 conv (M=64 -> 25) + bias + softmax(25) -------
// (unchanged from round 7: scalar weight loads, LDS only for reduction)
__global__ __launch_bounds__(512) void encoder_kernel(
    const float* __restrict__ t1, const float* __restrict__ w2,
    const float* __restrict__ b2, float* __restrict__ ker) {
  __shared__ float red[8][KK][64];   // 51.2 KB, reduction only
  const int tid = threadIdx.x;
  const int ow  = tid & 63;
  const int mg  = tid >> 6;          // wave index 0..7 -> 8 m per wave
  const int b   = blockIdx.x >> 6;
  const int oh  = blockIdx.x & 63;

  float acc[KK];
#pragma unroll
  for (int k = 0; k < KK; ++k) acc[k] = 0.f;

  const float* tb = t1 + (size_t)b * Mq * HWq;
  const int iwb = 2 * ow - 1;

  for (int mi = 0; mi < 8; ++mi) {
    const int m = __builtin_amdgcn_readfirstlane(mg * 8 + mi);
    const float* tm = tb + (size_t)m * HWq;
    const float* wm = w2 + m * 9;    // w2[k*576 + m*9 + dh*3 + dw]
#pragma unroll
    for (int dh = 0; dh < 3; ++dh) {
      int ih = 2 * oh + dh - 1;
      if ((unsigned)ih < (unsigned)Hq) {
        const float* tr = tm + ih * Wq;
        float v0 = (ow > 0) ? tr[iwb] : 0.f;
        float v1 = tr[iwb + 1];
        float v2 = tr[iwb + 2];
        const float* wr = wm + dh * 3;   // uniform base
#pragma unroll
        for (int k = 0; k < KK; ++k) {
          acc[k] += v0 * wr[k * 576 + 0];
          acc[k] += v1 * wr[k * 576 + 1];
          acc[k] += v2 * wr[k * 576 + 2];
        }
      }
    }
  }
#pragma unroll
  for (int k = 0; k < KK; ++k) red[mg][k][ow] = acc[k];
  __syncthreads();
  if (tid < 64) {
    float lg[KK];
#pragma unroll
    for (int k = 0; k < KK; ++k) {
      float s = b2[k];
#pragma unroll
      for (int g = 0; g < 8; ++g) s += red[g][k][tid];
      lg[k] = s;
    }
    float mx = lg[0];
#pragma unroll
    for (int k = 1; k < KK; ++k) mx = fmaxf(mx, lg[k]);
    float s = 0.f;
#pragma unroll
    for (int k = 0; k < KK; ++k) { lg[k] = __expf(lg[k] - mx); s += lg[k]; }
    float inv = 1.f / s;
    float* kb = ker + (size_t)b * KK * NHW + oh * NW + tid;
#pragma unroll
    for (int k = 0; k < KK; ++k) kb[k * NHW] = lg[k] * inv;
  }
}

// --------- Kernel C: CARAFE reassembly, LDS x-slab (unchanged from R7) ------
#define RSL_ROWS 19
#define RSL_CSZ  (RSL_ROWS * Wq)      // 2432 floats per channel slab
__global__ __launch_bounds__(256) void reassemble_kernel(
    const float* __restrict__ x, const float* __restrict__ ker,
    float* __restrict__ out) {
  __shared__ float xsl[8 * RSL_CSZ + 8];   // 76 KB + pad
  const int tid = threadIdx.x;
  const int bid = blockIdx.x;
  const int cg  = bid & 31;
  const int ohg = (bid >> 5) & 7;
  const int b   = bid >> 8;
  const int r0  = 16 * ohg - 2;            // first slab row = x row r0

  const int zlo = (r0 < 0) ? -r0 : 0;
  const int zhi = (r0 + RSL_ROWS > Hq) ? (r0 + RSL_ROWS - Hq) : 0;
  if (zlo > 0) {
    for (int c = 0; c < 8; ++c)
      for (int i = tid; i < zlo * Wq; i += 256) xsl[c * RSL_CSZ + i] = 0.f;
  }
  if (zhi > 0) {
    for (int c = 0; c < 8; ++c)
      for (int i = tid; i < zhi * Wq; i += 256)
        xsl[c * RSL_CSZ + (RSL_ROWS - zhi) * Wq + i] = 0.f;
  }
  const int vs = (r0 > 0) ? r0 : 0;
  const int ve = (r0 + RSL_ROWS < Hq) ? (r0 + RSL_ROWS) : Hq;
  const int nvec = ((ve - vs) * Wq) >> 2;          // float4 count
  const int loff = (vs - r0) * Wq;
  for (int c = 0; c < 8; ++c) {
    const float* g = x + ((size_t)(b * Cq + cg * 8 + c)) * HWq + vs * Wq;
    float* d = xsl + c * RSL_CSZ + loff;
    for (int i = tid; i < nvec; i += 256) {
      float4 v = *(const float4*)(g + 4 * i);
      *(float4*)(d + 4 * i) = v;
    }
  }

  const int ow = tid & 63;
  const int rq = tid >> 6;                 // 0..3 -> out rows oh, oh+1
  const int oh = 8 * ohg + 2 * rq;
  float kr0[KK], kr1[KK];
  const float* kb = ker + (size_t)b * KK * NHW + oh * NW + ow;
#pragma unroll
  for (int k = 0; k < KK; ++k) { kr0[k] = kb[k * NHW]; kr1[k] = kb[k * NHW + NW]; }

  __syncthreads();

  const int jb = 4 * rq;
  const bool e0 = (ow > 0);
  const bool e4 = (ow < 63);
  const float2 z2 = make_float2(0.f, 0.f);

  for (int c = 0; c < 8; ++c) {
    const float* sl = xsl + c * RSL_CSZ;
    float a0 = 0.f, a1 = 0.f;
#pragma unroll
    for (int j = 0; j < 7; ++j) {
      const float* xr = sl + (jb + j) * Wq + 2 * ow - 2;
      float2 v01 = e0 ? *(const float2*)xr : z2;        // taps -2,-1
      float2 v23 = *(const float2*)(xr + 2);            // taps  0,+1
      float  v4  = e4 ? xr[4] : 0.f;                    // tap  +2
      if (j < 5) {
        a0 += v01.x * kr0[j*5+0]; a0 += v01.y * kr0[j*5+1];
        a0 += v23.x * kr0[j*5+2]; a0 += v23.y * kr0[j*5+3];
        a0 += v4    * kr0[j*5+4];
      }
      if (j >= 2) {
        int dy = j - 2;
        a1 += v01.x * kr1[dy*5+0]; a1 += v01.y * kr1[dy*5+1];
        a1 += v23.x * kr1[dy*5+2]; a1 += v23.y * kr1[dy*5+3];
        a1 += v4    * kr1[dy*5+4];
      }
    }
    float* op = out + ((size_t)(b * Cq + cg * 8 + c)) * NHW + oh * NW + ow;
    op[0]  = a0;
    op[NW] = a1;
  }
}

extern "C" void kernel_launch(void* const* d_in, const int* in_sizes, int n_in,
                              void* d_out, int out_size, void* d_ws, size_t ws_size,
                              hipStream_t stream) {
  const float* x  = (const float*)d_in[0];
  const float* w1 = (const float*)d_in[1];
  const float* b1 = (const float*)d_in[2];
  const float* w2 = (const float*)d_in[3];
  const float* b2 = (const float*)d_in[4];
  float* out = (float*)d_out;

  float* t1  = (float*)d_ws;                       // 8,388,608 floats
  float* ker = t1 + (size_t)Bq * Mq * HWq;         // 819,200 floats

  conv1x1_mfma<<<1024, 256, 0, stream>>>(x, w1, b1, t1);
  encoder_kernel<<<Bq * NH, 512, 0, stream>>>(t1, w2, b2, ker);
  reassemble_kernel<<<2048, 256, 0, stream>>>(x, ker, out);
}